// Round 7
// baseline (314.345 us; speedup 1.0000x reference)
//
#include <hip/hip_runtime.h>
#include <math.h>

#define E_ 8
#define T_ 4096
#define K_ 2048
#define I_ 768
#define TWOI 1536
#define NPAIR (2*T_)

typedef unsigned short u16;
typedef __attribute__((ext_vector_type(8))) __bf16 bf16x8;
typedef __attribute__((ext_vector_type(4))) float f32x4;
typedef __attribute__((ext_vector_type(8))) u16 u16x8;
typedef __attribute__((ext_vector_type(4))) int int4v;
typedef __attribute__((ext_vector_type(4))) float float4v;

typedef __attribute__((address_space(3))) u16 lds_u16;
typedef __attribute__((address_space(1))) const u16 g_u16;

__device__ inline void gld16(const u16* g, u16* l) {
    __builtin_amdgcn_global_load_lds((g_u16*)g, (lds_u16*)l, 16, 0, 0);
}

// inline-asm LDS read: invisible to SIInsertWaitcnts' LDS-DMA aliasing,
// so no compiler vmcnt drain is inserted before read phases (rule #18:
// we provide lgkmcnt(0)+sched_barrier ourselves).
__device__ inline u16x8 ds128(unsigned byteOff) {
    u16x8 r;
    asm volatile("ds_read_b128 %0, %1" : "=v"(r) : "v"(byteOff));
    return r;
}

#define FENCE asm volatile("" ::: "memory")
#define BARR do { FENCE; __builtin_amdgcn_s_barrier(); __builtin_amdgcn_sched_barrier(0); } while (0)
#define VM6  asm volatile("s_waitcnt vmcnt(6)" ::: "memory")
#define LGKM0 do { asm volatile("s_waitcnt lgkmcnt(0)" ::: "memory"); __builtin_amdgcn_sched_barrier(0); } while (0)

__device__ inline u16 f2bf(float x) {
    unsigned u = __builtin_bit_cast(unsigned, x);
    unsigned r = 0x7fffu + ((u >> 16) & 1u);
    u += r;
    return (u16)(u >> 16);
}
__device__ inline float bf2f(u16 b) {
    unsigned u = ((unsigned)b) << 16;
    return __builtin_bit_cast(float, u);
}

// ---------------- routing ----------------
__global__ void k_zero(int* __restrict__ p, int n) {
    int i = blockIdx.x * 256 + threadIdx.x;
    if (i < n) p[i] = 0;
}

__global__ void k_route(const float* __restrict__ logits, int* __restrict__ tid2,
                        float* __restrict__ tw, int* __restrict__ counts) {
    int t = blockIdx.x * 256 + threadIdx.x;
    if (t >= T_) return;
    float l[E_];
#pragma unroll
    for (int e = 0; e < E_; ++e) l[e] = logits[t * E_ + e];
    int i0 = 0; float m0 = l[0];
#pragma unroll
    for (int e = 1; e < E_; ++e) if (l[e] > m0) { m0 = l[e]; i0 = e; }
    int i1 = -1; float m1 = -1e30f;
#pragma unroll
    for (int e = 0; e < E_; ++e) if (e != i0 && l[e] > m1) { m1 = l[e]; i1 = e; }
    float w0 = 1.0f / (1.0f + expf(m1 - m0));
    float w1 = 1.0f - w0;
    tid2[t * 2 + 0] = i0; tid2[t * 2 + 1] = i1;
    tw[t * 2 + 0] = w0;  tw[t * 2 + 1] = w1;
    atomicAdd(&counts[i0], 1);
    atomicAdd(&counts[i1], 1);
}

__global__ void k_scan(const int* __restrict__ counts, int* __restrict__ offsets) {
    if (threadIdx.x == 0) {
        int s = 0;
        for (int e = 0; e < E_; ++e) { offsets[e] = s; s += counts[e]; }
        offsets[E_] = s;
    }
}

__global__ void k_lists(const int* __restrict__ tid2, const int* __restrict__ offsets,
                        int* __restrict__ cursors, int* __restrict__ pairTok) {
    int t = blockIdx.x * 256 + threadIdx.x;
    if (t >= T_) return;
#pragma unroll
    for (int s = 0; s < 2; ++s) {
        int e = tid2[t * 2 + s];
        int pos = atomicAdd(&cursors[e], 1);
        pairTok[offsets[e] + pos] = (t << 1) | s;
    }
}

// ---------------- dequant conversions ----------------
__global__ void k_cvt_w13(const int* __restrict__ q, const float* __restrict__ alpha,
                          u16* __restrict__ wb) {
    long idx = ((long)blockIdx.x * 256 + threadIdx.x) * 8;
    int k = (int)(idx & (K_ - 1));
    int e = (int)(idx / ((long)TWOI * K_));
    const int4v* qp = (const int4v*)(q + idx);
    int4v q0 = qp[0], q1 = qp[1];
    const float4v* ap = (const float4v*)(alpha + e * K_ + k);
    float4v a0 = ap[0], a1 = ap[1];
    u16x8 r;
    r[0] = f2bf((float)(q0[0] - 1) * a0[0]);
    r[1] = f2bf((float)(q0[1] - 1) * a0[1]);
    r[2] = f2bf((float)(q0[2] - 1) * a0[2]);
    r[3] = f2bf((float)(q0[3] - 1) * a0[3]);
    r[4] = f2bf((float)(q1[0] - 1) * a1[0]);
    r[5] = f2bf((float)(q1[1] - 1) * a1[1]);
    r[6] = f2bf((float)(q1[2] - 1) * a1[2]);
    r[7] = f2bf((float)(q1[3] - 1) * a1[3]);
    *(u16x8*)(wb + idx) = r;
}

__global__ void k_cvt_w2(const int* __restrict__ q, const float* __restrict__ alpha,
                         u16* __restrict__ wb) {
    long idx = ((long)blockIdx.x * 256 + threadIdx.x) * 8;
    int i = (int)(idx % I_);
    int e = (int)(idx / ((long)K_ * I_));
    const int4v* qp = (const int4v*)(q + idx);
    int4v q0 = qp[0], q1 = qp[1];
    const float4v* ap = (const float4v*)(alpha + e * I_ + i);
    float4v a0 = ap[0], a1 = ap[1];
    u16x8 r;
    r[0] = f2bf((float)(q0[0] - 1) * a0[0]);
    r[1] = f2bf((float)(q0[1] - 1) * a0[1]);
    r[2] = f2bf((float)(q0[2] - 1) * a0[2]);
    r[3] = f2bf((float)(q0[3] - 1) * a0[3]);
    r[4] = f2bf((float)(q1[0] - 1) * a1[0]);
    r[5] = f2bf((float)(q1[1] - 1) * a1[1]);
    r[6] = f2bf((float)(q1[2] - 1) * a1[2]);
    r[7] = f2bf((float)(q1[3] - 1) * a1[3]);
    *(u16x8*)(wb + idx) = r;
}

__global__ void k_cvt_x(const float* __restrict__ x, u16* __restrict__ xb) {
    long idx = ((long)blockIdx.x * 256 + threadIdx.x) * 8;
    const float4v* xp = (const float4v*)(x + idx);
    float4v x0 = xp[0], x1 = xp[1];
    u16x8 r;
    r[0] = f2bf(x0[0]); r[1] = f2bf(x0[1]); r[2] = f2bf(x0[2]); r[3] = f2bf(x0[3]);
    r[4] = f2bf(x1[0]); r[5] = f2bf(x1[1]); r[6] = f2bf(x1[2]); r[7] = f2bf(x1[3]);
    *(u16x8*)(xb + idx) = r;
}

// ---------------- 256x256 8-phase grouped GEMM template ----------------
// C[m][n] = sum_k A[m][k] * B[n][k]   (B^T layout, both row-major stride KD)
// Expert pinned to XCD: e = bid & 7 (round-robin block->XCD dispatch).
template<int KD, int NCH, int NT, bool GATHER, bool SCATTER>
__global__ __launch_bounds__(512, 2) void k_gemm8(
    const u16* __restrict__ A, const u16* __restrict__ B,
    const int* __restrict__ pairTok, const int* __restrict__ offsets,
    u16* __restrict__ C)
{
    constexpr int ND = NCH * 256;
    int bid = blockIdx.x;
    int e  = bid & 7;
    int r_ = bid >> 3;
    int mc = r_ / NCH;
    int n0 = (r_ % NCH) * 256;
    int base = offsets[e];
    int cnt  = offsets[e + 1] - base;
    int m0 = mc * 256;
    if (m0 >= cnt) return;

    __shared__ __attribute__((aligned(16))) u16 As[2][256][64];  // 64 KB
    __shared__ __attribute__((aligned(16))) u16 Bs[2][256][64];  // 64 KB

    int tid = threadIdx.x;
    int lane = tid & 63;
    int wid = tid >> 6;          // 0..7
    int wr = wid >> 2, wc = wid & 3;
    int l15 = lane & 15;

    // --- staging source pointers (pre-swizzled global col; linear LDS dest) ---
    const u16* srcA[2][2];
    const u16* srcB[2][2];
#pragma unroll
    for (int h = 0; h < 2; ++h)
#pragma unroll
        for (int j = 0; j < 2; ++j) {
            int slot = j * 512 + tid;
            int row = slot >> 3, ch = slot & 7;
            int colsw = (ch ^ (row & 7)) * 8;
            int ra = m0 + h * 128 + row;
            if (ra >= cnt) ra = cnt - 1;
            long arow = GATHER ? (long)(pairTok[base + ra] >> 1) : (long)(base + ra);
            srcA[h][j] = A + arow * KD + colsw;
            srcB[h][j] = B + ((long)e * ND + n0 + h * 128 + row) * (long)KD + colsw;
        }
    u16* ldsA = &As[0][0][0];
    u16* ldsB = &Bs[0][0][0];
    int d0 = tid * 8, d1 = (512 + tid) * 8;

    auto stA = [&](int bs, int h, int t) {
        int k0 = (t < NT ? t : 0) * 64;
        u16* d = ldsA + bs * 16384 + h * 8192;
        gld16(srcA[h][0] + k0, d + d0);
        gld16(srcA[h][1] + k0, d + d1);
    };
    auto stB = [&](int bs, int h, int t) {
        int k0 = (t < NT ? t : 0) * 64;
        u16* d = ldsB + bs * 16384 + h * 8192;
        gld16(srcB[h][0] + k0, d + d0);
        gld16(srcB[h][1] + k0, d + d1);
    };

    // LDS byte bases for asm reads
    unsigned aBase = (unsigned)(unsigned long long)(lds_u16*)&As[0][0][0];
    unsigned bBase = (unsigned)(unsigned long long)(lds_u16*)&Bs[0][0][0];

    int kc0 = ((((lane >> 4) & 3) * 8)) ^ ((lane & 7) * 8);   // elements
    int kc1 = (32 + (((lane >> 4) & 3) * 8)) ^ ((lane & 7) * 8);

    bf16x8 a[4][2], b[4][2];
    f32x4 acc[8][4];
#pragma unroll
    for (int mf = 0; mf < 8; ++mf)
#pragma unroll
        for (int nf = 0; nf < 4; ++nf)
            acc[mf][nf] = (f32x4){0.f, 0.f, 0.f, 0.f};

    auto rdA = [&](int bs, int h64) {
#pragma unroll
        for (int mf = 0; mf < 4; ++mf) {
            unsigned rb = aBase + (unsigned)(bs * 16384 + (wr * 128 + h64 + mf * 16 + l15) * 64) * 2u;
            a[mf][0] = __builtin_bit_cast(bf16x8, ds128(rb + (unsigned)kc0 * 2u));
            a[mf][1] = __builtin_bit_cast(bf16x8, ds128(rb + (unsigned)kc1 * 2u));
        }
    };
    auto rdB = [&](int bs) {
#pragma unroll
        for (int nf = 0; nf < 4; ++nf) {
            unsigned rb = bBase + (unsigned)(bs * 16384 + (wc * 64 + nf * 16 + l15) * 64) * 2u;
            b[nf][0] = __builtin_bit_cast(bf16x8, ds128(rb + (unsigned)kc0 * 2u));
            b[nf][1] = __builtin_bit_cast(bf16x8, ds128(rb + (unsigned)kc1 * 2u));
        }
    };
    auto mmq = [&](int mh, int nh) {
        __builtin_amdgcn_s_setprio(1);
#pragma unroll
        for (int mf = 0; mf < 4; ++mf)
#pragma unroll
            for (int nf = 0; nf < 2; ++nf)
#pragma unroll
                for (int ks = 0; ks < 2; ++ks)
                    acc[mh * 4 + mf][nh * 2 + nf] = __builtin_amdgcn_mfma_f32_16x16x32_bf16(
                        a[mf][ks], b[nh * 2 + nf][ks], acc[mh * 4 + mf][nh * 2 + nf], 0, 0, 0);
        __builtin_amdgcn_s_setprio(0);
    };

    // prologue: tile0 full + tile1 {B0,B1,A0}; vmcnt(6) forces tile0 landed
    stB(0, 0, 0); stB(0, 1, 0); stA(0, 0, 0); stA(0, 1, 0);
    stB(1, 0, 1); stB(1, 1, 1); stA(1, 0, 1);
    VM6; BARR;

#pragma unroll 1
    for (int i = 0; i < NT / 2; ++i) {
        int tO = 2 * i + 1, t2 = 2 * i + 2, t3 = 2 * i + 3;
        // ph1: read E (buf0) A-lo + B-all; stage A1(O)->buf1
        rdA(0, 0); rdB(0);
        stA(1, 1, tO);
        BARR; LGKM0; mmq(0, 0); BARR;
        // ph2: stage B0(E')->buf0 (buf0 B dead after ph1)
        stB(0, 0, t2);
        BARR; mmq(0, 1); BARR;
        // ph3: read E A-hi; stage B1(E')
        rdA(0, 64);
        stB(0, 1, t2);
        BARR; LGKM0; mmq(1, 0); BARR;
        // ph4: stage A0(E'); vmcnt(6) -> tile O fully landed
        stA(0, 0, t2);
        VM6; BARR; mmq(1, 1); BARR;
        // ph5: read O (buf1) A-lo + B-all; stage A1(E')
        rdA(1, 0); rdB(1);
        stA(0, 1, t2);
        BARR; LGKM0; mmq(0, 0); BARR;
        // ph6: stage B0(O')->buf1 (buf1 B dead after ph5)
        stB(1, 0, t3);
        BARR; mmq(0, 1); BARR;
        // ph7: read O A-hi; stage B1(O')
        rdA(1, 64);
        stB(1, 1, t3);
        BARR; LGKM0; mmq(1, 0); BARR;
        // ph8: stage A0(O'); vmcnt(6) -> tile E' fully landed
        stA(1, 0, t3);
        VM6; BARR; mmq(1, 1); BARR;
    }

    // epilogue
#pragma unroll
    for (int mf = 0; mf < 8; ++mf)
#pragma unroll
        for (int nf = 0; nf < 4; ++nf)
#pragma unroll
            for (int rg = 0; rg < 4; ++rg) {
                int r = wr * 128 + mf * 16 + (lane >> 4) * 4 + rg;
                if (m0 + r < cnt) {
                    int col = n0 + wc * 64 + nf * 16 + l15;
                    u16 v = f2bf(acc[mf][nf][rg]);
                    if (SCATTER) {
                        int pt = pairTok[base + m0 + r];
                        C[(long)pt * ND + col] = v;
                    } else {
                        C[(long)(base + m0 + r) * ND + col] = v;
                    }
                }
            }
}

// ---------------- silu(g)*u activation ----------------
__global__ void k_act(const u16* __restrict__ h, u16* __restrict__ ab) {
    long idx = ((long)blockIdx.x * 256 + threadIdx.x) * 8;  // over NPAIR*I
    int p = (int)(idx / I_);
    int i = (int)(idx - (long)p * I_);
    u16x8 gv = *(const u16x8*)(h + (long)p * TWOI + i);
    u16x8 uv = *(const u16x8*)(h + (long)p * TWOI + I_ + i);
    u16x8 r;
#pragma unroll
    for (int j = 0; j < 8; ++j) {
        float g = bf2f(gv[j]);
        float u = bf2f(uv[j]);
        r[j] = f2bf(g / (1.0f + expf(-g)) * u);
    }
    *(u16x8*)(ab + (long)p * I_ + i) = r;
}

// ---------------- combine ----------------
__global__ void k_combine(const u16* __restrict__ yb, const float* __restrict__ tw,
                          float* __restrict__ out) {
    long idx = ((long)blockIdx.x * 256 + threadIdx.x) * 8;
    int t = (int)(idx >> 11);
    float w0 = tw[t * 2 + 0];
    float w1 = tw[t * 2 + 1];
    u16x8 y0 = *(const u16x8*)(yb + (long)(2 * t) * K_ + (idx & (K_ - 1)));
    u16x8 y1 = *(const u16x8*)(yb + (long)(2 * t + 1) * K_ + (idx & (K_ - 1)));
    float4v o0, o1;
#pragma unroll
    for (int j = 0; j < 4; ++j) o0[j] = w0 * bf2f(y0[j]) + w1 * bf2f(y1[j]);
#pragma unroll
    for (int j = 0; j < 4; ++j) o1[j] = w0 * bf2f(y0[4 + j]) + w1 * bf2f(y1[4 + j]);
    *(float4v*)(out + idx) = o0;
    *(float4v*)(out + idx + 4) = o1;
}

// ---------------- launch ----------------
extern "C" void kernel_launch(void* const* d_in, const int* in_sizes, int n_in,
                              void* d_out, int out_size, void* d_ws, size_t ws_size,
                              hipStream_t stream) {
    const float* x       = (const float*)d_in[0];
    const float* logits  = (const float*)d_in[1];
    const int*   w13q    = (const int*)d_in[2];
    const int*   w2q     = (const int*)d_in[3];
    const float* alpha13 = (const float*)d_in[4];
    const float* alpha2  = (const float*)d_in[5];
    float* out = (float*)d_out;

    char* ws = (char*)d_ws;
    u16* wb13 = (u16*)(ws);                         // 50331648 B
    u16* wb2  = (u16*)(ws + 50331648);              // 25165824 B
    u16* xb   = (u16*)(ws + 75497472);              // 16777216 B
    u16* ab   = (u16*)(ws + 92274688);              // 12582912 B
    u16* yb   = (u16*)(ws + 104857600);             // 33554432 B
    u16* h    = yb;                                 // aliases yb: h dead before gemm2 writes yb
    int* pairTok = (int*)(ws + 138412032);          // 8192 ints
    int* tid2    = pairTok + NPAIR;                 // 8192 ints
    float* tw    = (float*)(tid2 + NPAIR);          // 8192 floats
    int* counts  = (int*)(tw + NPAIR);              // 8
    int* offsets = counts + 8;                      // 9
    int* cursors = offsets + 9;                     // 8

    // routing
    k_zero<<<1, 64, 0, stream>>>(counts, 25);
    k_route<<<T_ / 256, 256, 0, stream>>>(logits, tid2, tw, counts);
    k_scan<<<1, 64, 0, stream>>>(counts, offsets);
    k_lists<<<T_ / 256, 256, 0, stream>>>(tid2, offsets, cursors, pairTok);

    // dequant
    k_cvt_w13<<<(8L * TWOI * K_) / 8 / 256, 256, 0, stream>>>(w13q, alpha13, wb13);
    k_cvt_w2<<<(8L * K_ * I_) / 8 / 256, 256, 0, stream>>>(w2q, alpha2, wb2);
    k_cvt_x<<<((long)T_ * K_) / 8 / 256, 256, 0, stream>>>(x, xb);

    // grouped GEMM1 (M x 1536 x 2048), 8-phase 256^2, gather A rows by token
    k_gemm8<K_, TWOI / 256, K_ / 64, true, false>
        <<<(T_ / 256) * 8 * (TWOI / 256), 512, 0, stream>>>(xb, wb13, pairTok, offsets, h);

    // silu(g)*u
    k_act<<<((long)NPAIR * I_) / 8 / 256, 256, 0, stream>>>(h, ab);

    // grouped GEMM2 (M x 2048 x 768), 8-phase 256^2, scatter C rows by pair
    k_gemm8<I_, K_ / 256, I_ / 64, false, true>
        <<<(T_ / 256) * 8 * (K_ / 256), 512, 0, stream>>>(ab, wb2, pairTok, offsets, yb);

    // combine
    k_combine<<<((long)T_ * K_) / 8 / 256, 256, 0, stream>>>(yb, tw, out);
}

// Round 8
// 265.568 us; speedup vs baseline: 1.1837x; 1.1837x over previous
//
#include <hip/hip_runtime.h>
#include <math.h>

#define E_ 8
#define T_ 4096
#define K_ 2048
#define I_ 768
#define TWOI 1536
#define NPAIR (2*T_)

typedef unsigned short u16;
typedef __attribute__((ext_vector_type(8))) __bf16 bf16x8;
typedef __attribute__((ext_vector_type(4))) float f32x4;
typedef __attribute__((ext_vector_type(8))) u16 u16x8;
typedef __attribute__((ext_vector_type(4))) int int4v;
typedef __attribute__((ext_vector_type(4))) float float4v;

typedef __attribute__((address_space(3))) u16 lds_u16;
typedef __attribute__((address_space(1))) const u16 g_u16;

__device__ inline void gld16(const u16* g, u16* l) {
    __builtin_amdgcn_global_load_lds((g_u16*)g, (lds_u16*)l, 16, 0, 0);
}

__device__ inline u16 f2bf(float x) {
    unsigned u = __builtin_bit_cast(unsigned, x);
    unsigned r = 0x7fffu + ((u >> 16) & 1u);
    u += r;
    return (u16)(u >> 16);
}
__device__ inline float bf2f(u16 b) {
    unsigned u = ((unsigned)b) << 16;
    return __builtin_bit_cast(float, u);
}

// ---------------- routing ----------------
__global__ void k_zero(int* __restrict__ p, int n) {
    int i = blockIdx.x * 256 + threadIdx.x;
    if (i < n) p[i] = 0;
}

__global__ void k_route(const float* __restrict__ logits, int* __restrict__ tid2,
                        float* __restrict__ tw, int* __restrict__ counts) {
    int t = blockIdx.x * 256 + threadIdx.x;
    if (t >= T_) return;
    float l[E_];
#pragma unroll
    for (int e = 0; e < E_; ++e) l[e] = logits[t * E_ + e];
    int i0 = 0; float m0 = l[0];
#pragma unroll
    for (int e = 1; e < E_; ++e) if (l[e] > m0) { m0 = l[e]; i0 = e; }
    int i1 = -1; float m1 = -1e30f;
#pragma unroll
    for (int e = 0; e < E_; ++e) if (e != i0 && l[e] > m1) { m1 = l[e]; i1 = e; }
    float w0 = 1.0f / (1.0f + expf(m1 - m0));
    float w1 = 1.0f - w0;
    tid2[t * 2 + 0] = i0; tid2[t * 2 + 1] = i1;
    tw[t * 2 + 0] = w0;  tw[t * 2 + 1] = w1;
    atomicAdd(&counts[i0], 1);
    atomicAdd(&counts[i1], 1);
}

__global__ void k_scan(const int* __restrict__ counts, int* __restrict__ offsets) {
    if (threadIdx.x == 0) {
        int s = 0;
        for (int e = 0; e < E_; ++e) { offsets[e] = s; s += counts[e]; }
        offsets[E_] = s;
    }
}

__global__ void k_lists(const int* __restrict__ tid2, const int* __restrict__ offsets,
                        int* __restrict__ cursors, int* __restrict__ pairTok) {
    int t = blockIdx.x * 256 + threadIdx.x;
    if (t >= T_) return;
#pragma unroll
    for (int s = 0; s < 2; ++s) {
        int e = tid2[t * 2 + s];
        int pos = atomicAdd(&cursors[e], 1);
        pairTok[offsets[e] + pos] = (t << 1) | s;
    }
}

// ---------------- dequant conversions ----------------
__global__ void k_cvt_w13(const int* __restrict__ q, const float* __restrict__ alpha,
                          u16* __restrict__ wb) {
    long idx = ((long)blockIdx.x * 256 + threadIdx.x) * 8;
    int k = (int)(idx & (K_ - 1));
    int e = (int)(idx / ((long)TWOI * K_));
    const int4v* qp = (const int4v*)(q + idx);
    int4v q0 = qp[0], q1 = qp[1];
    const float4v* ap = (const float4v*)(alpha + e * K_ + k);
    float4v a0 = ap[0], a1 = ap[1];
    u16x8 r;
    r[0] = f2bf((float)(q0[0] - 1) * a0[0]);
    r[1] = f2bf((float)(q0[1] - 1) * a0[1]);
    r[2] = f2bf((float)(q0[2] - 1) * a0[2]);
    r[3] = f2bf((float)(q0[3] - 1) * a0[3]);
    r[4] = f2bf((float)(q1[0] - 1) * a1[0]);
    r[5] = f2bf((float)(q1[1] - 1) * a1[1]);
    r[6] = f2bf((float)(q1[2] - 1) * a1[2]);
    r[7] = f2bf((float)(q1[3] - 1) * a1[3]);
    *(u16x8*)(wb + idx) = r;
}

__global__ void k_cvt_w2(const int* __restrict__ q, const float* __restrict__ alpha,
                         u16* __restrict__ wb) {
    long idx = ((long)blockIdx.x * 256 + threadIdx.x) * 8;
    int i = (int)(idx % I_);
    int e = (int)(idx / ((long)K_ * I_));
    const int4v* qp = (const int4v*)(q + idx);
    int4v q0 = qp[0], q1 = qp[1];
    const float4v* ap = (const float4v*)(alpha + e * I_ + i);
    float4v a0 = ap[0], a1 = ap[1];
    u16x8 r;
    r[0] = f2bf((float)(q0[0] - 1) * a0[0]);
    r[1] = f2bf((float)(q0[1] - 1) * a0[1]);
    r[2] = f2bf((float)(q0[2] - 1) * a0[2]);
    r[3] = f2bf((float)(q0[3] - 1) * a0[3]);
    r[4] = f2bf((float)(q1[0] - 1) * a1[0]);
    r[5] = f2bf((float)(q1[1] - 1) * a1[1]);
    r[6] = f2bf((float)(q1[2] - 1) * a1[2]);
    r[7] = f2bf((float)(q1[3] - 1) * a1[3]);
    *(u16x8*)(wb + idx) = r;
}

__global__ void k_cvt_x(const float* __restrict__ x, u16* __restrict__ xb) {
    long idx = ((long)blockIdx.x * 256 + threadIdx.x) * 8;
    const float4v* xp = (const float4v*)(x + idx);
    float4v x0 = xp[0], x1 = xp[1];
    u16x8 r;
    r[0] = f2bf(x0[0]); r[1] = f2bf(x0[1]); r[2] = f2bf(x0[2]); r[3] = f2bf(x0[3]);
    r[4] = f2bf(x1[0]); r[5] = f2bf(x1[1]); r[6] = f2bf(x1[2]); r[7] = f2bf(x1[3]);
    *(u16x8*)(xb + idx) = r;
}

// ---------------- 256x256 2-phase grouped GEMM (m230-V0 structure) ----------------
// C[m][n] = sum_k A[m][k] * B[n][k]  (B^T layout, row-major stride KD)
// ACT=true (gemm1): B tile = [128 gate rows | 128 up rows] of w13; epilogue
//   computes silu(g)*u via swizzled-LDS repack and writes ab (n0 = nch*128).
// ACT=false (gemm2): plain; C rows scattered by pairTok; n0 = nch*256.
template<int KD, int NCH, int NT, bool GATHER, bool ACT>
__global__ __launch_bounds__(512, 2) void k_g2(
    const u16* __restrict__ A, const u16* __restrict__ B,
    const int* __restrict__ pairTok, const int* __restrict__ offsets,
    u16* __restrict__ C)
{
    int bid = blockIdx.x;
    int e  = bid & 7;                 // expert -> XCD pin
    int r_ = bid >> 3;
    int mc = r_ / NCH;
    int nch = r_ % NCH;
    int base = offsets[e];
    int cnt  = offsets[e + 1] - base;
    int m0 = mc * 256;
    if (m0 >= cnt) return;
    int n0 = nch * (ACT ? 128 : 256);

    __shared__ __attribute__((aligned(16))) u16 SH[2][2][256][64];  // 128 KB
    u16* ldsA = &SH[0][0][0][0];
    u16* ldsB = &SH[1][0][0][0];

    int tid = threadIdx.x;
    int lane = tid & 63;
    int wid = tid >> 6;
    int wr = wid >> 2, wc = wid & 3;
    int l15 = lane & 15;

    // staging sources: pre-swizzled global col, linear LDS dest
    const u16* srcA[2][2];
    const u16* srcB[2][2];
#pragma unroll
    for (int h = 0; h < 2; ++h)
#pragma unroll
        for (int j = 0; j < 2; ++j) {
            int slot = j * 512 + tid;
            int row = slot >> 3, ch = slot & 7;
            int colsw = (ch ^ (row & 7)) * 8;
            int ra = m0 + h * 128 + row;
            if (ra >= cnt) ra = cnt - 1;
            long arow = GATHER ? (long)(pairTok[base + ra] >> 1) : (long)(base + ra);
            srcA[h][j] = A + arow * KD + colsw;
            long brow = ACT ? ((long)e * TWOI + h * I_ + nch * 128 + row)
                            : ((long)e * (NCH * 256) + nch * 256 + h * 128 + row);
            srcB[h][j] = B + brow * (long)KD + colsw;
        }
    int d0 = tid * 8, d1 = (512 + tid) * 8;

    auto stage = [&](int bs, int t) {
        int k0 = t * 64;
        u16* dA = ldsA + bs * 16384;
        u16* dB = ldsB + bs * 16384;
#pragma unroll
        for (int h = 0; h < 2; ++h) {
            gld16(srcA[h][0] + k0, dA + h * 8192 + d0);
            gld16(srcA[h][1] + k0, dA + h * 8192 + d1);
            gld16(srcB[h][0] + k0, dB + h * 8192 + d0);
            gld16(srcB[h][1] + k0, dB + h * 8192 + d1);
        }
    };

    int kc0 = ((((lane >> 4) & 3) * 8)) ^ ((lane & 7) * 8);
    int kc1 = (32 + (((lane >> 4) & 3) * 8)) ^ ((lane & 7) * 8);

    bf16x8 a[4][2], b[4][2];
    f32x4 acc[8][4];
#pragma unroll
    for (int mf = 0; mf < 8; ++mf)
#pragma unroll
        for (int nf = 0; nf < 4; ++nf)
            acc[mf][nf] = (f32x4){0.f, 0.f, 0.f, 0.f};

    auto rdA = [&](int bs, int h64) {
#pragma unroll
        for (int mf = 0; mf < 4; ++mf) {
            const u16* p = ldsA + bs * 16384 + (wr * 128 + h64 + mf * 16 + l15) * 64;
            a[mf][0] = __builtin_bit_cast(bf16x8, *(const u16x8*)(p + kc0));
            a[mf][1] = __builtin_bit_cast(bf16x8, *(const u16x8*)(p + kc1));
        }
    };
    auto rdB = [&](int bs) {
#pragma unroll
        for (int nf = 0; nf < 4; ++nf) {
            const u16* p = ldsB + bs * 16384 + (wc * 64 + nf * 16 + l15) * 64;
            b[nf][0] = __builtin_bit_cast(bf16x8, *(const u16x8*)(p + kc0));
            b[nf][1] = __builtin_bit_cast(bf16x8, *(const u16x8*)(p + kc1));
        }
    };
    auto mm = [&](int mh) {
#pragma unroll
        for (int ks = 0; ks < 2; ++ks)
#pragma unroll
            for (int mf = 0; mf < 4; ++mf)
#pragma unroll
                for (int nf = 0; nf < 4; ++nf)
                    acc[mh * 4 + mf][nf] = __builtin_amdgcn_mfma_f32_16x16x32_bf16(
                        a[mf][ks], b[nf][ks], acc[mh * 4 + mf][nf], 0, 0, 0);
    };
    auto compute = [&](int bs) {
        rdB(bs);
        rdA(bs, 0);
        mm(0);
        rdA(bs, 64);
        mm(1);
    };

    // 2-phase double-buffered loop (NT even)
    stage(0, 0);
    __syncthreads();
#pragma unroll 1
    for (int t = 0; t < NT; t += 2) {
        stage(1, t + 1);
        compute(0);
        __syncthreads();
        if (t + 2 < NT) stage(0, t + 2);
        compute(1);
        __syncthreads();
    }

    // ---- epilogue: acc -> LDS (XOR-swizzled repack) -> wide stores ----
    u16* flat = ldsA;  // 131072 B contiguous = [256][256] u16
#pragma unroll
    for (int mf = 0; mf < 8; ++mf)
#pragma unroll
        for (int nf = 0; nf < 4; ++nf)
#pragma unroll
            for (int rg = 0; rg < 4; ++rg) {
                int row = wr * 128 + mf * 16 + (lane >> 4) * 4 + rg;
                int col = wc * 64 + nf * 16 + l15;
                flat[row * 256 + (col ^ ((row & 7) << 3))] = f2bf(acc[mf][nf][rg]);
            }
    __syncthreads();
    int row = tid >> 1;
    if (m0 + row < cnt) {
        int xr = (row & 7) << 3;
        int half = tid & 1;
        if (ACT) {
            u16* dst = C + (long)(base + m0 + row) * I_ + n0 + half * 64;
#pragma unroll
            for (int jj = 0; jj < 8; ++jj) {
                u16x8 gv = *(const u16x8*)&flat[row * 256 + ((half * 64 + jj * 8) ^ xr)];
                u16x8 uv = *(const u16x8*)&flat[row * 256 + ((128 + half * 64 + jj * 8) ^ xr)];
                u16x8 r;
#pragma unroll
                for (int q = 0; q < 8; ++q) {
                    float g = bf2f(gv[q]), u = bf2f(uv[q]);
                    r[q] = f2bf(g / (1.0f + expf(-g)) * u);
                }
                *(u16x8*)(dst + jj * 8) = r;
            }
        } else {
            int pt = pairTok[base + m0 + row];
            u16* dst = C + (long)pt * (NCH * 256) + n0 + half * 128;
#pragma unroll
            for (int jj = 0; jj < 16; ++jj) {
                *(u16x8*)(dst + jj * 8) =
                    *(const u16x8*)&flat[row * 256 + ((half * 128 + jj * 8) ^ xr)];
            }
        }
    }
}

// ---------------- combine ----------------
__global__ void k_combine(const u16* __restrict__ yb, const float* __restrict__ tw,
                          float* __restrict__ out) {
    long idx = ((long)blockIdx.x * 256 + threadIdx.x) * 8;
    int t = (int)(idx >> 11);
    float w0 = tw[t * 2 + 0];
    float w1 = tw[t * 2 + 1];
    u16x8 y0 = *(const u16x8*)(yb + (long)(2 * t) * K_ + (idx & (K_ - 1)));
    u16x8 y1 = *(const u16x8*)(yb + (long)(2 * t + 1) * K_ + (idx & (K_ - 1)));
    float4v o0, o1;
#pragma unroll
    for (int j = 0; j < 4; ++j) o0[j] = w0 * bf2f(y0[j]) + w1 * bf2f(y1[j]);
#pragma unroll
    for (int j = 0; j < 4; ++j) o1[j] = w0 * bf2f(y0[4 + j]) + w1 * bf2f(y1[4 + j]);
    *(float4v*)(out + idx) = o0;
    *(float4v*)(out + idx + 4) = o1;
}

// ---------------- launch ----------------
extern "C" void kernel_launch(void* const* d_in, const int* in_sizes, int n_in,
                              void* d_out, int out_size, void* d_ws, size_t ws_size,
                              hipStream_t stream) {
    const float* x       = (const float*)d_in[0];
    const float* logits  = (const float*)d_in[1];
    const int*   w13q    = (const int*)d_in[2];
    const int*   w2q     = (const int*)d_in[3];
    const float* alpha13 = (const float*)d_in[4];
    const float* alpha2  = (const float*)d_in[5];
    float* out = (float*)d_out;

    char* ws = (char*)d_ws;
    u16* wb13 = (u16*)(ws);                         // 50331648 B
    u16* wb2  = (u16*)(ws + 50331648);              // 25165824 B
    u16* xb   = (u16*)(ws + 75497472);              // 16777216 B
    u16* ab   = (u16*)(ws + 92274688);              // 12582912 B
    u16* yb   = (u16*)(ws + 104857600);             // 33554432 B
    int* pairTok = (int*)(ws + 138412032);          // 8192 ints
    int* tid2    = pairTok + NPAIR;                 // 8192 ints
    float* tw    = (float*)(tid2 + NPAIR);          // 8192 floats
    int* counts  = (int*)(tw + NPAIR);              // 8
    int* offsets = counts + 8;                      // 9
    int* cursors = offsets + 9;                     // 8

    // routing
    k_zero<<<1, 64, 0, stream>>>(counts, 25);
    k_route<<<T_ / 256, 256, 0, stream>>>(logits, tid2, tw, counts);
    k_scan<<<1, 64, 0, stream>>>(counts, offsets);
    k_lists<<<T_ / 256, 256, 0, stream>>>(tid2, offsets, cursors, pairTok);

    // dequant
    k_cvt_w13<<<(8L * TWOI * K_) / 8 / 256, 256, 0, stream>>>(w13q, alpha13, wb13);
    k_cvt_w2<<<(8L * K_ * I_) / 8 / 256, 256, 0, stream>>>(w2q, alpha2, wb2);
    k_cvt_x<<<((long)T_ * K_) / 8 / 256, 256, 0, stream>>>(x, xb);

    // grouped GEMM1 (M x [128g|128u] x 2048) + fused silu*u -> ab
    k_g2<K_, I_ / 128, K_ / 64, true, true>
        <<<8 * (T_ / 256) * (I_ / 128), 512, 0, stream>>>(xb, wb13, pairTok, offsets, ab);

    // grouped GEMM2 (M x 2048 x 768) -> yb scattered by pair
    k_g2<I_, K_ / 256, I_ / 64, false, false>
        <<<8 * (T_ / 256) * (K_ / 256), 512, 0, stream>>>(ab, wb2, pairTok, offsets, yb);

    // combine
    k_combine<<<((long)T_ * K_) / 8 / 256, 256, 0, stream>>>(yb, tw, out);
}

// Round 9
// 250.232 us; speedup vs baseline: 1.2562x; 1.0613x over previous
//
#include <hip/hip_runtime.h>
#include <math.h>

#define E_ 8
#define T_ 4096
#define K_ 2048
#define I_ 768
#define TWOI 1536
#define NPAIR (2*T_)

typedef unsigned short u16;
typedef signed char i8;
typedef __attribute__((ext_vector_type(8))) __bf16 bf16x8;
typedef __attribute__((ext_vector_type(4))) float f32x4;
typedef __attribute__((ext_vector_type(4))) int i32x4;
typedef __attribute__((ext_vector_type(8))) u16 u16x8;
typedef __attribute__((ext_vector_type(4))) int int4v;
typedef __attribute__((ext_vector_type(4))) float float4v;

typedef __attribute__((address_space(3))) char lds_c;
typedef __attribute__((address_space(1))) const char g_c;

__device__ inline void gld16(const void* g, void* l) {
    __builtin_amdgcn_global_load_lds((g_c*)g, (lds_c*)l, 16, 0, 0);
}

__device__ inline u16 f2bf(float x) {
    unsigned u = __builtin_bit_cast(unsigned, x);
    unsigned r = 0x7fffu + ((u >> 16) & 1u);
    u += r;
    return (u16)(u >> 16);
}
__device__ inline float bf2f(u16 b) {
    unsigned u = ((unsigned)b) << 16;
    return __builtin_bit_cast(float, u);
}

// ---------------- routing ----------------
__global__ void k_zero(int* __restrict__ p, int n) {
    int i = blockIdx.x * 256 + threadIdx.x;
    if (i < n) p[i] = 0;
}

__global__ void k_route(const float* __restrict__ logits, int* __restrict__ tid2,
                        float* __restrict__ tw, int* __restrict__ counts) {
    int t = blockIdx.x * 256 + threadIdx.x;
    if (t >= T_) return;
    float l[E_];
#pragma unroll
    for (int e = 0; e < E_; ++e) l[e] = logits[t * E_ + e];
    int i0 = 0; float m0 = l[0];
#pragma unroll
    for (int e = 1; e < E_; ++e) if (l[e] > m0) { m0 = l[e]; i0 = e; }
    int i1 = -1; float m1 = -1e30f;
#pragma unroll
    for (int e = 0; e < E_; ++e) if (e != i0 && l[e] > m1) { m1 = l[e]; i1 = e; }
    float w0 = 1.0f / (1.0f + expf(m1 - m0));
    float w1 = 1.0f - w0;
    tid2[t * 2 + 0] = i0; tid2[t * 2 + 1] = i1;
    tw[t * 2 + 0] = w0;  tw[t * 2 + 1] = w1;
    atomicAdd(&counts[i0], 1);
    atomicAdd(&counts[i1], 1);
}

__global__ void k_scan(const int* __restrict__ counts, int* __restrict__ offsets) {
    if (threadIdx.x == 0) {
        int s = 0;
        for (int e = 0; e < E_; ++e) { offsets[e] = s; s += counts[e]; }
        offsets[E_] = s;
    }
}

__global__ void k_lists(const int* __restrict__ tid2, const int* __restrict__ offsets,
                        int* __restrict__ cursors, int* __restrict__ pairTok) {
    int t = blockIdx.x * 256 + threadIdx.x;
    if (t >= T_) return;
#pragma unroll
    for (int s = 0; s < 2; ++s) {
        int e = tid2[t * 2 + s];
        int pos = atomicAdd(&cursors[e], 1);
        pairTok[offsets[e] + pos] = (t << 1) | s;
    }
}

// ---------------- dequant conversions ----------------
// w13 -> pure ternary codes i8 (alpha folded into activations)
__global__ void k_cvt_w13(const int* __restrict__ q, i8* __restrict__ wc) {
    long idx = ((long)blockIdx.x * 256 + threadIdx.x) * 8;
    const int4v* qp = (const int4v*)(q + idx);
    int4v q0 = qp[0], q1 = qp[1];
    unsigned long long pk = 0;
#pragma unroll
    for (int j = 0; j < 4; ++j)
        pk |= ((unsigned long long)(unsigned char)(char)(q0[j] - 1)) << (8 * j);
#pragma unroll
    for (int j = 0; j < 4; ++j)
        pk |= ((unsigned long long)(unsigned char)(char)(q1[j] - 1)) << (8 * (4 + j));
    *(unsigned long long*)(wc + idx) = pk;
}

// w2 -> bf16 with alpha2 folded (gemm2 stays bf16)
__global__ void k_cvt_w2(const int* __restrict__ q, const float* __restrict__ alpha,
                         u16* __restrict__ wb) {
    long idx = ((long)blockIdx.x * 256 + threadIdx.x) * 8;
    int i = (int)(idx % I_);
    int e = (int)(idx / ((long)K_ * I_));
    const int4v* qp = (const int4v*)(q + idx);
    int4v q0 = qp[0], q1 = qp[1];
    const float4v* ap = (const float4v*)(alpha + e * I_ + i);
    float4v a0 = ap[0], a1 = ap[1];
    u16x8 r;
    r[0] = f2bf((float)(q0[0] - 1) * a0[0]);
    r[1] = f2bf((float)(q0[1] - 1) * a0[1]);
    r[2] = f2bf((float)(q0[2] - 1) * a0[2]);
    r[3] = f2bf((float)(q0[3] - 1) * a0[3]);
    r[4] = f2bf((float)(q1[0] - 1) * a1[0]);
    r[5] = f2bf((float)(q1[1] - 1) * a1[1]);
    r[6] = f2bf((float)(q1[2] - 1) * a1[2]);
    r[7] = f2bf((float)(q1[3] - 1) * a1[3]);
    *(u16x8*)(wb + idx) = r;
}

// per-pair-row quantization of x*alpha13[e] -> i8 + row scale
__global__ __launch_bounds__(256) void k_qx(
    const float* __restrict__ x, const float* __restrict__ a13,
    const int* __restrict__ pairTok, const int* __restrict__ offsets,
    i8* __restrict__ xq, float* __restrict__ sx)
{
    int p = blockIdx.x;
    int e = 0;
#pragma unroll
    for (int j = 1; j < E_; ++j) if (p >= offsets[j]) e = j;
    int tok = pairTok[p] >> 1;
    int tid = threadIdx.x;
    int i0 = tid * 8;

    float xa[8];
    {
        const float4v* xp = (const float4v*)(x + (long)tok * K_ + i0);
        const float4v* ap = (const float4v*)(a13 + (long)e * K_ + i0);
        float4v x0 = xp[0], x1 = xp[1], a0 = ap[0], a1 = ap[1];
#pragma unroll
        for (int j = 0; j < 4; ++j) { xa[j] = x0[j] * a0[j]; xa[4 + j] = x1[j] * a1[j]; }
    }
    float m = 0.f;
#pragma unroll
    for (int j = 0; j < 8; ++j) m = fmaxf(m, fabsf(xa[j]));
#pragma unroll
    for (int off = 32; off >= 1; off >>= 1) m = fmaxf(m, __shfl_xor(m, off));
    __shared__ float wm[4];
    if ((tid & 63) == 0) wm[tid >> 6] = m;
    __syncthreads();
    m = fmaxf(fmaxf(wm[0], wm[1]), fmaxf(wm[2], wm[3]));
    float inv = (m > 0.f) ? 127.0f / m : 0.f;
    unsigned long long pk = 0;
#pragma unroll
    for (int j = 0; j < 8; ++j) {
        int qv = __float2int_rn(xa[j] * inv);
        pk |= ((unsigned long long)(unsigned char)(char)qv) << (8 * j);
    }
    *(unsigned long long*)(xq + (long)p * K_ + i0) = pk;
    if (tid == 0) sx[p] = m / 127.0f;
}

// ---------------- GEMM1: i8 256x256 2-phase, fused silu*u ----------------
// h[m, n] = (sum_k xq[m,k]*code[n,k]) * sx[m];  B-tile = [128 gate | 128 up]
__global__ __launch_bounds__(512, 2) void k_g1i8(
    const i8* __restrict__ A,       // xq [NPAIR][K] list order
    const i8* __restrict__ B,       // wc13 [E][2I][K]
    const int* __restrict__ offsets, const float* __restrict__ sx,
    u16* __restrict__ C)            // ab [NPAIR][I]
{
    int bid = blockIdx.x;
    int e  = bid & 7;
    int r_ = bid >> 3;
    int mc = r_ / 6;
    int nch = r_ % 6;
    int base = offsets[e];
    int cnt  = offsets[e + 1] - base;
    int m0 = mc * 256;
    if (m0 >= cnt) return;
    int n0 = nch * 128;

    __shared__ __attribute__((aligned(16))) i8 As[2][256][128];  // 64 KB
    __shared__ __attribute__((aligned(16))) i8 Bs[2][256][128];  // 64 KB

    int tid = threadIdx.x;
    int lane = tid & 63;
    int wid = tid >> 6;
    int wr = wid >> 2, wc = wid & 3;
    int l15 = lane & 15;

    // staging sources: pre-swizzled global col (16B chunks), linear LDS dest
    const i8* srcA[4];
    const i8* srcB[4];
#pragma unroll
    for (int j = 0; j < 4; ++j) {
        int chunk = j * 512 + tid;          // 0..2047
        int row = chunk >> 3, ch = chunk & 7;
        int colsw = (ch ^ (row & 7)) * 16;  // i8 elements == bytes
        int ra = m0 + row; if (ra >= cnt) ra = cnt - 1;
        srcA[j] = A + (long)(base + ra) * K_ + colsw;
        int grow = e * TWOI + (row >> 7) * I_ + n0 + (row & 127);
        srcB[j] = B + (long)grow * K_ + colsw;
    }

    auto stage = [&](int bs, int t) {
        int k0 = t * 128;
        i8* dA = &As[bs][0][0];
        i8* dB = &Bs[bs][0][0];
#pragma unroll
        for (int j = 0; j < 4; ++j) {
            gld16(srcA[j] + k0, dA + j * 8192 + tid * 16);
            gld16(srcB[j] + k0, dB + j * 8192 + tid * 16);
        }
    };

    int kq16 = ((lane >> 4) & 3) * 16;

    i32x4 a[4][2], b[4][2];
    i32x4 acc[8][4];
#pragma unroll
    for (int mf = 0; mf < 8; ++mf)
#pragma unroll
        for (int nf = 0; nf < 4; ++nf)
            acc[mf][nf] = (i32x4){0, 0, 0, 0};

    auto rdA = [&](int bs, int h64) {
#pragma unroll
        for (int mf = 0; mf < 4; ++mf) {
            int row = wr * 128 + h64 + mf * 16 + l15;
            const i8* p = &As[bs][row][0];
            int xr = (row & 7) << 4;
            a[mf][0] = *(const i32x4*)(p + ((kq16) ^ xr));
            a[mf][1] = *(const i32x4*)(p + ((64 + kq16) ^ xr));
        }
    };
    auto rdB = [&](int bs) {
#pragma unroll
        for (int nf = 0; nf < 4; ++nf) {
            int row = wc * 64 + nf * 16 + l15;
            const i8* p = &Bs[bs][row][0];
            int xr = (row & 7) << 4;
            b[nf][0] = *(const i32x4*)(p + ((kq16) ^ xr));
            b[nf][1] = *(const i32x4*)(p + ((64 + kq16) ^ xr));
        }
    };
    auto mm = [&](int mh) {
#pragma unroll
        for (int ks = 0; ks < 2; ++ks)
#pragma unroll
            for (int mf = 0; mf < 4; ++mf)
#pragma unroll
                for (int nf = 0; nf < 4; ++nf)
                    acc[mh * 4 + mf][nf] = __builtin_amdgcn_mfma_i32_16x16x64_i8(
                        a[mf][ks], b[nf][ks], acc[mh * 4 + mf][nf], 0, 0, 0);
    };
    auto compute = [&](int bs) {
        rdB(bs);
        rdA(bs, 0);
        mm(0);
        rdA(bs, 64);
        mm(1);
    };

    // 2-phase double-buffered loop, NT = 16 (K=2048, BK=128)
    stage(0, 0);
    __syncthreads();
#pragma unroll 1
    for (int t = 0; t < 16; t += 2) {
        stage(1, t + 1);
        compute(0);
        __syncthreads();
        if (t + 2 < 16) stage(0, t + 2);
        compute(1);
        __syncthreads();
    }

    // epilogue: raw acc -> bf16 in LDS (swizzled), then silu(g)*u with row scale
    u16* flat = (u16*)&As[0][0][0];  // 131072 B = [256][256] u16
#pragma unroll
    for (int mf = 0; mf < 8; ++mf)
#pragma unroll
        for (int nf = 0; nf < 4; ++nf)
#pragma unroll
            for (int rg = 0; rg < 4; ++rg) {
                int row = wr * 128 + mf * 16 + (lane >> 4) * 4 + rg;
                int col = wc * 64 + nf * 16 + l15;
                flat[row * 256 + (col ^ ((row & 7) << 3))] = f2bf((float)acc[mf][nf][rg]);
            }
    __syncthreads();
    int row = tid >> 1;
    if (m0 + row < cnt) {
        float s = sx[base + m0 + row];
        int xr = (row & 7) << 3;
        int half = tid & 1;
        u16* dst = C + (long)(base + m0 + row) * I_ + n0 + half * 64;
#pragma unroll
        for (int jj = 0; jj < 8; ++jj) {
            u16x8 gv = *(const u16x8*)&flat[row * 256 + ((half * 64 + jj * 8) ^ xr)];
            u16x8 uv = *(const u16x8*)&flat[row * 256 + ((128 + half * 64 + jj * 8) ^ xr)];
            u16x8 r;
#pragma unroll
            for (int q = 0; q < 8; ++q) {
                float g = bf2f(gv[q]) * s, u = bf2f(uv[q]) * s;
                r[q] = f2bf(g / (1.0f + expf(-g)) * u);
            }
            *(u16x8*)(dst + jj * 8) = r;
        }
    }
}

// ---------------- GEMM2: bf16 256x256 2-phase (unchanged from R8) ----------------
template<int KD, int NCH, int NT>
__global__ __launch_bounds__(512, 2) void k_g2(
    const u16* __restrict__ A, const u16* __restrict__ B,
    const int* __restrict__ pairTok, const int* __restrict__ offsets,
    u16* __restrict__ C)
{
    int bid = blockIdx.x;
    int e  = bid & 7;
    int r_ = bid >> 3;
    int mc = r_ / NCH;
    int nch = r_ % NCH;
    int base = offsets[e];
    int cnt  = offsets[e + 1] - base;
    int m0 = mc * 256;
    if (m0 >= cnt) return;
    int n0 = nch * 256;

    __shared__ __attribute__((aligned(16))) u16 SH[2][2][256][64];  // 128 KB
    u16* ldsA = &SH[0][0][0][0];
    u16* ldsB = &SH[1][0][0][0];

    int tid = threadIdx.x;
    int lane = tid & 63;
    int wid = tid >> 6;
    int wr = wid >> 2, wc = wid & 3;
    int l15 = lane & 15;

    const u16* srcA[2][2];
    const u16* srcB[2][2];
#pragma unroll
    for (int h = 0; h < 2; ++h)
#pragma unroll
        for (int j = 0; j < 2; ++j) {
            int slot = j * 512 + tid;
            int row = slot >> 3, ch = slot & 7;
            int colsw = (ch ^ (row & 7)) * 8;
            int ra = m0 + h * 128 + row;
            if (ra >= cnt) ra = cnt - 1;
            srcA[h][j] = A + (long)(base + ra) * KD + colsw;
            long brow = (long)e * (NCH * 256) + n0 + h * 128 + row;
            srcB[h][j] = B + brow * (long)KD + colsw;
        }
    int d0 = tid * 8, d1 = (512 + tid) * 8;

    auto stage = [&](int bs, int t) {
        int k0 = t * 64;
        u16* dA = ldsA + bs * 16384;
        u16* dB = ldsB + bs * 16384;
#pragma unroll
        for (int h = 0; h < 2; ++h) {
            gld16(srcA[h][0] + k0, dA + h * 8192 + d0);
            gld16(srcA[h][1] + k0, dA + h * 8192 + d1);
            gld16(srcB[h][0] + k0, dB + h * 8192 + d0);
            gld16(srcB[h][1] + k0, dB + h * 8192 + d1);
        }
    };

    int kc0 = ((((lane >> 4) & 3) * 8)) ^ ((lane & 7) * 8);
    int kc1 = (32 + (((lane >> 4) & 3) * 8)) ^ ((lane & 7) * 8);

    bf16x8 a[4][2], b[4][2];
    f32x4 acc[8][4];
#pragma unroll
    for (int mf = 0; mf < 8; ++mf)
#pragma unroll
        for (int nf = 0; nf < 4; ++nf)
            acc[mf][nf] = (f32x4){0.f, 0.f, 0.f, 0.f};

    auto rdA = [&](int bs, int h64) {
#pragma unroll
        for (int mf = 0; mf < 4; ++mf) {
            const u16* p = ldsA + bs * 16384 + (wr * 128 + h64 + mf * 16 + l15) * 64;
            a[mf][0] = __builtin_bit_cast(bf16x8, *(const u16x8*)(p + kc0));
            a[mf][1] = __builtin_bit_cast(bf16x8, *(const u16x8*)(p + kc1));
        }
    };
    auto rdB = [&](int bs) {
#pragma unroll
        for (int nf = 0; nf < 4; ++nf) {
            const u16* p = ldsB + bs * 16384 + (wc * 64 + nf * 16 + l15) * 64;
            b[nf][0] = __builtin_bit_cast(bf16x8, *(const u16x8*)(p + kc0));
            b[nf][1] = __builtin_bit_cast(bf16x8, *(const u16x8*)(p + kc1));
        }
    };
    auto mm = [&](int mh) {
#pragma unroll
        for (int ks = 0; ks < 2; ++ks)
#pragma unroll
            for (int mf = 0; mf < 4; ++mf)
#pragma unroll
                for (int nf = 0; nf < 4; ++nf)
                    acc[mh * 4 + mf][nf] = __builtin_amdgcn_mfma_f32_16x16x32_bf16(
                        a[mf][ks], b[nf][ks], acc[mh * 4 + mf][nf], 0, 0, 0);
    };
    auto compute = [&](int bs) {
        rdB(bs);
        rdA(bs, 0);
        mm(0);
        rdA(bs, 64);
        mm(1);
    };

    stage(0, 0);
    __syncthreads();
#pragma unroll 1
    for (int t = 0; t < NT; t += 2) {
        stage(1, t + 1);
        compute(0);
        __syncthreads();
        if (t + 2 < NT) stage(0, t + 2);
        compute(1);
        __syncthreads();
    }

    u16* flat = ldsA;
#pragma unroll
    for (int mf = 0; mf < 8; ++mf)
#pragma unroll
        for (int nf = 0; nf < 4; ++nf)
#pragma unroll
            for (int rg = 0; rg < 4; ++rg) {
                int row = wr * 128 + mf * 16 + (lane >> 4) * 4 + rg;
                int col = wc * 64 + nf * 16 + l15;
                flat[row * 256 + (col ^ ((row & 7) << 3))] = f2bf(acc[mf][nf][rg]);
            }
    __syncthreads();
    int row = tid >> 1;
    if (m0 + row < cnt) {
        int xr = (row & 7) << 3;
        int half = tid & 1;
        int pt = pairTok[base + m0 + row];
        u16* dst = C + (long)pt * (NCH * 256) + n0 + half * 128;
#pragma unroll
        for (int jj = 0; jj < 16; ++jj) {
            *(u16x8*)(dst + jj * 8) =
                *(const u16x8*)&flat[row * 256 + ((half * 128 + jj * 8) ^ xr)];
        }
    }
}

// ---------------- combine ----------------
__global__ void k_combine(const u16* __restrict__ yb, const float* __restrict__ tw,
                          float* __restrict__ out) {
    long idx = ((long)blockIdx.x * 256 + threadIdx.x) * 8;
    int t = (int)(idx >> 11);
    float w0 = tw[t * 2 + 0];
    float w1 = tw[t * 2 + 1];
    u16x8 y0 = *(const u16x8*)(yb + (long)(2 * t) * K_ + (idx & (K_ - 1)));
    u16x8 y1 = *(const u16x8*)(yb + (long)(2 * t + 1) * K_ + (idx & (K_ - 1)));
    float4v o0, o1;
#pragma unroll
    for (int j = 0; j < 4; ++j) o0[j] = w0 * bf2f(y0[j]) + w1 * bf2f(y1[j]);
#pragma unroll
    for (int j = 0; j < 4; ++j) o1[j] = w0 * bf2f(y0[4 + j]) + w1 * bf2f(y1[4 + j]);
    *(float4v*)(out + idx) = o0;
    *(float4v*)(out + idx + 4) = o1;
}

// ---------------- launch ----------------
extern "C" void kernel_launch(void* const* d_in, const int* in_sizes, int n_in,
                              void* d_out, int out_size, void* d_ws, size_t ws_size,
                              hipStream_t stream) {
    const float* x       = (const float*)d_in[0];
    const float* logits  = (const float*)d_in[1];
    const int*   w13q    = (const int*)d_in[2];
    const int*   w2q     = (const int*)d_in[3];
    const float* alpha13 = (const float*)d_in[4];
    const float* alpha2  = (const float*)d_in[5];
    float* out = (float*)d_out;

    char* ws = (char*)d_ws;
    i8*  wc13 = (i8*)(ws);                          // 25165824 B (codes i8)
    u16* wb2  = (u16*)(ws + 50331648);              // 25165824 B (bf16, alpha folded)
    i8*  xq   = (i8*)(ws + 75497472);               // 16777216 B (i8 per-pair rows)
    u16* ab   = (u16*)(ws + 92274688);              // 12582912 B
    u16* yb   = (u16*)(ws + 104857600);             // 33554432 B
    int* pairTok = (int*)(ws + 138412032);          // 8192 ints
    int* tid2    = pairTok + NPAIR;                 // 8192 ints
    float* tw    = (float*)(tid2 + NPAIR);          // 8192 floats
    int* counts  = (int*)(tw + NPAIR);              // 8
    int* offsets = counts + 8;                      // 9
    int* cursors = offsets + 9;                     // 8
    float* sx    = (float*)(cursors + 8);           // 8192 floats

    // routing
    k_zero<<<1, 64, 0, stream>>>(counts, 25);
    k_route<<<T_ / 256, 256, 0, stream>>>(logits, tid2, tw, counts);
    k_scan<<<1, 64, 0, stream>>>(counts, offsets);
    k_lists<<<T_ / 256, 256, 0, stream>>>(tid2, offsets, cursors, pairTok);

    // weight conversions
    k_cvt_w13<<<(8L * TWOI * K_) / 8 / 256, 256, 0, stream>>>(w13q, wc13);
    k_cvt_w2<<<(8L * K_ * I_) / 8 / 256, 256, 0, stream>>>(w2q, alpha2, wb2);

    // per-pair-row i8 quantization of x*alpha13
    k_qx<<<NPAIR, 256, 0, stream>>>(x, alpha13, pairTok, offsets, xq, sx);

    // GEMM1 i8 (M x [128g|128u] x 2048) + fused silu*u -> ab
    k_g1i8<<<8 * (T_ / 256) * 6, 512, 0, stream>>>(xq, wc13, offsets, sx, ab);

    // GEMM2 bf16 (M x 2048 x 768) -> yb scattered by pair
    k_g2<I_, K_ / 256, I_ / 64>
        <<<8 * (T_ / 256) * (K_ / 256), 512, 0, stream>>>(ab, wb2, pairTok, offsets, yb);

    // combine
    k_combine<<<((long)T_ * K_) / 8 / 256, 256, 0, stream>>>(yb, tw, out);
}